// Round 3
// baseline (763.254 us; speedup 1.0000x reference)
//
#include <hip/hip_runtime.h>
#include <hip/hip_bf16.h>

#define D 256
#define NC 512
#define NROWS 131072L

// out layout (fp32 elements), reference return order
#define OFF_ZQ   0L
#define OFF_VQ   33554432L
#define OFF_CM   33554433L
#define OFF_IDX  33554434L
#define OFF_HIST 33685506L

// ws float offsets
#define WS_LOSS 0
#define WS_HIST 64
#define WS_E2   576
#define WS_CNT  1088
#define WS_AMB  1152
#define WS_FIDX 132224
#define WS_BWS  263296
#define WS_NEED (459904L * 4)

#define MARGIN 0.0625f

typedef __attribute__((ext_vector_type(8))) short bf16x8;
typedef __attribute__((ext_vector_type(4))) float f32x4;

__device__ __forceinline__ unsigned short f2bf(float f) {
    union { float f; unsigned int u; } a; a.f = f;
    return (unsigned short)((a.u + 0x7FFFu + ((a.u >> 16) & 1u)) >> 16);  // RNE
}
__device__ __forceinline__ float bf2f(unsigned short h) {
    union { unsigned int u; float f; } a; a.u = ((unsigned int)h) << 16; return a.f;
}

__global__ void vq_init(float* __restrict__ ws) {
    int i = blockIdx.x * 1024 + threadIdx.x;
    if (i < 1089) ws[i] = 0.0f;   // loss, hist, (e2 region), ambig count
}

__global__ void vq_e2(const float* __restrict__ e, float* __restrict__ e2) {
    int c = blockIdx.x;
    int l = threadIdx.x;  // 64 threads
    float4 v = *(const float4*)(e + c * D + l * 4);
    float s = v.x * v.x + v.y * v.y + v.z * v.z + v.w * v.w;
    #pragma unroll
    for (int off = 32; off; off >>= 1) s += __shfl_xor(s, off);
    if (l == 0) e2[c] = s;
}

// B_ws[n][768] = [eh(256) | eh(256) | el(256)]  (bf16 raw ushort)
__global__ void vq_convB(const float* __restrict__ e, unsigned short* __restrict__ B) {
    int n = blockIdx.x, d = threadIdx.x;
    float v = e[n * D + d];
    unsigned short h = f2bf(v);
    unsigned short l = f2bf(v - bf2f(h));
    B[n * 768 + d]       = h;
    B[n * 768 + 256 + d] = h;
    B[n * 768 + 512 + d] = l;
}

// K'=768 segments: s<8 -> zh*eh, 8<=s<16 -> zl*eh, s>=16 -> zh*el
__global__ __launch_bounds__(512, 4)
void vq_gemm(const float* __restrict__ z, const unsigned short* __restrict__ Bws,
             const float* __restrict__ e2, int* __restrict__ fidx,
             int* __restrict__ acnt, int* __restrict__ alist) {
    __shared__ __align__(16) unsigned short As[64 * 32];    // 4 KB
    __shared__ __align__(16) unsigned short Bs[512 * 32];   // 32 KB
    __shared__ float red[64 * 8 * 3];                        // 6 KB

    const int tid = threadIdx.x;
    const int w = tid >> 6, l = tid & 63, q = l >> 4, ln = l & 15;
    const long row0 = (long)blockIdx.x * 64;

    f32x4 acc[4][4];
    #pragma unroll
    for (int mt = 0; mt < 4; ++mt)
        #pragma unroll
        for (int nt = 0; nt < 4; ++nt) acc[mt][nt] = (f32x4){0.f, 0.f, 0.f, 0.f};

    const int am = tid >> 3;          // A row (0..63)
    const int ac = (tid & 7) * 4;     // A col within 32-slab

    for (int s = 0; s < 24; ++s) {
        const int d0 = (s < 8 ? s : (s < 16 ? s - 8 : s - 16)) * 32;
        const int k0 = s * 32;
        const bool lo = (s >= 8) && (s < 16);
        __syncthreads();              // previous slab fully consumed
        // ---- A stage: fp32 -> bf16 hi/lo on the fly, contiguous LDS ----
        {
            float4 av = *(const float4*)(z + (row0 + am) * D + d0 + ac);
            unsigned short h0 = f2bf(av.x), h1 = f2bf(av.y), h2 = f2bf(av.z), h3 = f2bf(av.w);
            if (lo) {
                h0 = f2bf(av.x - bf2f(h0)); h1 = f2bf(av.y - bf2f(h1));
                h2 = f2bf(av.z - bf2f(h2)); h3 = f2bf(av.w - bf2f(h3));
            }
            *(ushort4*)&As[tid * 4] = make_ushort4(h0, h1, h2, h3);
        }
        // ---- B stage: 32 KB slab, contiguous 16B lane chunks ----
        #pragma unroll
        for (int j = 0; j < 4; ++j) {
            int idx = (tid + j * 512) * 8;           // ushort linear index in slab
            int n = idx >> 5, kc = idx & 31;
            uint4 bvv = *(const uint4*)(Bws + n * 768 + k0 + kc);
            *(uint4*)&Bs[idx] = bvv;
        }
        __syncthreads();
        // ---- frags + 16 MFMA ----
        bf16x8 af[4], bfr[4];
        #pragma unroll
        for (int mt = 0; mt < 4; ++mt)
            af[mt] = *(const bf16x8*)&As[(mt * 16 + ln) * 32 + q * 8];
        #pragma unroll
        for (int nt = 0; nt < 4; ++nt)
            bfr[nt] = *(const bf16x8*)&Bs[(w * 64 + nt * 16 + ln) * 32 + q * 8];
        #pragma unroll
        for (int mt = 0; mt < 4; ++mt)
            #pragma unroll
            for (int nt = 0; nt < 4; ++nt)
                acc[mt][nt] = __builtin_amdgcn_mfma_f32_16x16x32_bf16(af[mt], bfr[nt], acc[mt][nt], 0, 0, 0);
    }

    // ---- per-row top-2 of sim = e2[col] - 2*dot within wave's 64 cols ----
    float e2v[4];
    #pragma unroll
    for (int nt = 0; nt < 4; ++nt) e2v[nt] = e2[w * 64 + nt * 16 + ln];

    #pragma unroll
    for (int mt = 0; mt < 4; ++mt) {
        #pragma unroll
        for (int r = 0; r < 4; ++r) {
            float v1 = -3.0e38f, v2 = -3.0e38f; int i1 = 0;
            #pragma unroll
            for (int nt = 0; nt < 4; ++nt) {
                float v = e2v[nt] - 2.0f * acc[mt][nt][r];
                int c = w * 64 + nt * 16 + ln;
                if (v > v1) { v2 = v1; v1 = v; i1 = c; }
                else if (v > v2) v2 = v;
            }
            #pragma unroll
            for (int off = 1; off < 16; off <<= 1) {   // 16-lane group butterfly
                float ov1 = __shfl_xor(v1, off);
                float ov2 = __shfl_xor(v2, off);
                int   oi1 = __shfl_xor(i1, off);
                if (ov1 > v1 || (ov1 == v1 && oi1 < i1)) {
                    v2 = fmaxf(v1, ov2); v1 = ov1; i1 = oi1;
                } else {
                    v2 = fmaxf(v2, ov1);
                }
            }
            if (ln == 0) {
                int rr = mt * 16 + q * 4 + r;          // C/D row mapping
                red[rr * 24 + w * 3 + 0] = v1;
                red[rr * 24 + w * 3 + 1] = (float)i1;
                red[rr * 24 + w * 3 + 2] = v2;
            }
        }
    }
    __syncthreads();
    // ---- cross-wave (8-way) reduce: final idx + ambiguity flag ----
    if (tid < 64) {
        float v1 = -3.0e38f, v2 = -3.0e38f; int i1 = 0;
        #pragma unroll
        for (int ww = 0; ww < 8; ++ww) {
            float rv1 = red[tid * 24 + ww * 3 + 0];
            int   ri  = (int)red[tid * 24 + ww * 3 + 1];
            float rv2 = red[tid * 24 + ww * 3 + 2];
            if (rv1 > v1 || (rv1 == v1 && ri < i1)) { v2 = fmaxf(v1, rv2); v1 = rv1; i1 = ri; }
            else v2 = fmaxf(v2, rv1);
        }
        fidx[row0 + tid] = i1;
        if (v1 - v2 < MARGIN) {
            int p = atomicAdd(acnt, 1);
            alist[p] = (int)(row0 + tid);
        }
    }
}

// exact fp32 re-argmax for margin-ambiguous rows
__global__ __launch_bounds__(256)
void vq_refine(const float* __restrict__ z, const float* __restrict__ e,
               const float* __restrict__ e2, const int* __restrict__ acnt,
               const int* __restrict__ alist, int* __restrict__ fidx) {
    __shared__ float zs[D];
    __shared__ float bv[256];
    __shared__ int   bi[256];
    const int t = threadIdx.x;
    const int n = *acnt;
    for (int j = blockIdx.x; j < n; j += gridDim.x) {
        const long row = alist[j];
        __syncthreads();
        zs[t] = z[row * D + t];
        __syncthreads();
        float best = -3.0e38f; int bidx = 0;
        for (int c = t; c < NC; c += 256) {
            float s0 = 0.f, s1 = 0.f, s2 = 0.f, s3 = 0.f;
            for (int d = 0; d < D; d += 4) {
                float4 ev = *(const float4*)(e + c * D + d);
                s0 = fmaf(zs[d],     ev.x, s0);
                s1 = fmaf(zs[d + 1], ev.y, s1);
                s2 = fmaf(zs[d + 2], ev.z, s2);
                s3 = fmaf(zs[d + 3], ev.w, s3);
            }
            float v = e2[c] - 2.0f * ((s0 + s1) + (s2 + s3));
            if (v > best || (v == best && c < bidx)) { best = v; bidx = c; }
        }
        bv[t] = best; bi[t] = bidx;
        __syncthreads();
        for (int off = 128; off; off >>= 1) {
            if (t < off) {
                if (bv[t + off] > bv[t] || (bv[t + off] == bv[t] && bi[t + off] < bi[t])) {
                    bv[t] = bv[t + off]; bi[t] = bi[t + off];
                }
            }
            __syncthreads();
        }
        if (t == 0) fidx[row] = bi[0];
        __syncthreads();
    }
}

__global__ __launch_bounds__(256)
void vq_epi(const float* __restrict__ z, const float* __restrict__ e,
            const int* __restrict__ fidx, float* __restrict__ out,
            float* __restrict__ loss, float* __restrict__ hist) {
    __shared__ float rs[4];
    const int t = threadIdx.x, lane = t & 63, w = t >> 6;
    const long row0 = (long)blockIdx.x * 8;
    float ls = 0.f;
    #pragma unroll
    for (int r = 0; r < 8; ++r) {
        const long row = row0 + r;
        const int idx = fidx[row];
        float zv = z[row * D + t];
        float ev = e[(long)idx * D + t];
        float dq = ev - zv;
        out[OFF_ZQ + row * D + t] = zv + dq;   // z + (z_q - z), matches np fp32
        ls += dq * dq;
        if (t == 0) {
            out[OFF_IDX + row] = (float)idx;
            atomicAdd(&hist[idx], 1.0f);
        }
    }
    #pragma unroll
    for (int off = 32; off; off >>= 1) ls += __shfl_xor(ls, off);
    if (lane == 0) rs[w] = ls;
    __syncthreads();
    if (t == 0) atomicAdd(loss, rs[0] + rs[1] + rs[2] + rs[3]);
}

__global__ void vq_fin(const float* __restrict__ ws, float* __restrict__ out) {
    int t = blockIdx.x * blockDim.x + threadIdx.x;
    if (t < NC) out[OFF_HIST + t] = ws[WS_HIST + t];
    if (t == NC) {
        float m = ws[WS_LOSS] / 33554432.0f;   // mean((z_q - z)^2)
        out[OFF_VQ] = m;
        out[OFF_CM] = 0.25f * m;
    }
}

// ================= fallback (ws too small): round-2 fp32 path =================
__global__ __launch_bounds__(256, 2)
void vq_main_fb(const float* __restrict__ z, const float* __restrict__ e,
                const float* __restrict__ e2, float* __restrict__ out,
                float* __restrict__ ws_loss, float* __restrict__ ws_hist) {
    __shared__ __align__(16) float z_s[32][D];
    __shared__ __align__(16) float e_s[16][NC + 4];
    __shared__ int   idx_s[32];
    __shared__ float red_s[4];
    const int tid = threadIdx.x, lane = tid & 63, w = tid >> 6;
    const long row0 = (long)blockIdx.x * 32;
    {
        const float4* zg = (const float4*)(z + row0 * D);
        float4* zs = (float4*)(&z_s[0][0]);
        #pragma unroll
        for (int i = 0; i < 8; ++i) zs[i * 256 + tid] = zg[i * 256 + tid];
    }
    float acc[8][8];
    #pragma unroll
    for (int r = 0; r < 8; ++r)
        #pragma unroll
        for (int c = 0; c < 8; ++c) acc[r][c] = 0.0f;
    const int r0 = w * 8, c_lo = lane * 4;
    for (int kc = 0; kc < D; kc += 16) {
        __syncthreads();
        #pragma unroll
        for (int p = 0; p < 8; ++p) {
            int c = p * 64 + (tid >> 2), kk4 = (tid & 3) * 4;
            float4 v = *(const float4*)(e + c * D + kc + kk4);
            e_s[kk4 + 0][c] = v.x; e_s[kk4 + 1][c] = v.y;
            e_s[kk4 + 2][c] = v.z; e_s[kk4 + 3][c] = v.w;
        }
        __syncthreads();
        #pragma unroll
        for (int k4 = 0; k4 < 16; k4 += 4) {
            float zr[8][4];
            #pragma unroll
            for (int r = 0; r < 8; ++r) *(float4*)zr[r] = *(const float4*)&z_s[r0 + r][kc + k4];
            #pragma unroll
            for (int kk = 0; kk < 4; ++kk) {
                float ev[8];
                *(float4*)&ev[0] = *(const float4*)&e_s[k4 + kk][c_lo];
                *(float4*)&ev[4] = *(const float4*)&e_s[k4 + kk][c_lo + 256];
                #pragma unroll
                for (int r = 0; r < 8; ++r)
                    #pragma unroll
                    for (int c = 0; c < 8; ++c) acc[r][c] = fmaf(zr[r][kk], ev[c], acc[r][c]);
            }
        }
    }
    float e2v[8];
    #pragma unroll
    for (int g = 0; g < 2; ++g)
        #pragma unroll
        for (int i = 0; i < 4; ++i) e2v[g * 4 + i] = e2[g * 256 + c_lo + i];
    #pragma unroll
    for (int r = 0; r < 8; ++r) {
        float bvv = -3.0e38f; int bc = 0;
        #pragma unroll
        for (int c = 0; c < 8; ++c) {
            int col = (c >> 2) * 256 + c_lo + (c & 3);
            float v = e2v[c] - 2.0f * acc[r][c];
            if (v > bvv) { bvv = v; bc = col; }
        }
        #pragma unroll
        for (int off = 32; off; off >>= 1) {
            float ov = __shfl_xor(bvv, off); int oc = __shfl_xor(bc, off);
            if (ov > bvv || (ov == bvv && oc < bc)) { bvv = ov; bc = oc; }
        }
        if (lane == 0) idx_s[r0 + r] = bc;
    }
    __syncthreads();
    if (tid < 32) {
        int bc = idx_s[tid];
        out[OFF_IDX + row0 + tid] = (float)bc;
        atomicAdd(&ws_hist[bc], 1.0f);
    }
    float lsum = 0.0f;
    for (int r = 0; r < 32; ++r) {
        int idx = idx_s[r];
        float ev = e[idx * D + tid];
        float zv = z_s[r][tid];
        float dq = ev - zv;
        out[OFF_ZQ + (row0 + r) * D + tid] = zv + dq;
        lsum += dq * dq;
    }
    #pragma unroll
    for (int off = 32; off; off >>= 1) lsum += __shfl_xor(lsum, off);
    if (lane == 0) red_s[w] = lsum;
    __syncthreads();
    if (tid == 0) atomicAdd(ws_loss, red_s[0] + red_s[1] + red_s[2] + red_s[3]);
}

__global__ void vq_init_fb(float* __restrict__ ws) {
    int t = threadIdx.x;
    if (t < 513) ws[t] = 0.0f;
}
__global__ void vq_fin_fb(const float* __restrict__ ws, float* __restrict__ out) {
    int t = blockIdx.x * blockDim.x + threadIdx.x;
    if (t < NC) out[OFF_HIST + t] = ws[1 + t];
    if (t == NC) {
        float m = ws[0] / 33554432.0f;
        out[OFF_VQ] = m; out[OFF_CM] = 0.25f * m;
    }
}

extern "C" void kernel_launch(void* const* d_in, const int* in_sizes, int n_in,
                              void* d_out, int out_size, void* d_ws, size_t ws_size,
                              hipStream_t stream) {
    const float* z = (const float*)d_in[0];
    const float* e = (const float*)d_in[1];
    float* out = (float*)d_out;
    float* ws  = (float*)d_ws;

    if (ws_size >= (size_t)WS_NEED) {
        float* loss = ws + WS_LOSS;
        float* hist = ws + WS_HIST;
        float* e2   = ws + WS_E2;
        int*   acnt = (int*)(ws + WS_CNT);
        int*   alist= (int*)(ws + WS_AMB);
        int*   fidx = (int*)(ws + WS_FIDX);
        unsigned short* Bws = (unsigned short*)(ws + WS_BWS);

        vq_init<<<2, 1024, 0, stream>>>(ws);
        vq_e2<<<NC, 64, 0, stream>>>(e, e2);
        vq_convB<<<NC, 256, 0, stream>>>(e, Bws);
        vq_gemm<<<2048, 512, 0, stream>>>(z, Bws, e2, fidx, acnt, alist);
        vq_refine<<<128, 256, 0, stream>>>(z, e, e2, acnt, alist, fidx);
        vq_epi<<<16384, 256, 0, stream>>>(z, e, fidx, out, loss, hist);
        vq_fin<<<3, 256, 0, stream>>>(ws, out);
    } else {
        float* ws_loss = ws;
        float* ws_hist = ws + 1;
        float* ws_e2   = ws + 513;
        vq_init_fb<<<1, 1024, 0, stream>>>(ws);
        vq_e2<<<NC, 64, 0, stream>>>(e, ws_e2);
        vq_main_fb<<<4096, 256, 0, stream>>>(z, e, ws_e2, out, ws_loss, ws_hist);
        vq_fin_fb<<<3, 256, 0, stream>>>(ws, out);
    }
}

// Round 4
// 511.847 us; speedup vs baseline: 1.4912x; 1.4912x over previous
//
#include <hip/hip_runtime.h>
#include <hip/hip_bf16.h>

#define D 256
#define NC 512
#define NROWS 131072L

// out layout (fp32 elements), reference return order
#define OFF_ZQ   0L
#define OFF_VQ   33554432L
#define OFF_CM   33554433L
#define OFF_IDX  33554434L
#define OFF_HIST 33685506L

// ws float offsets
#define WS_LPART 0        // [0, 2048)       per-block loss partials
#define WS_HIST  2048     // [2048, 2560)
#define WS_E2    2560     // [2560, 3072)
#define WS_CNT   3072     // ambig count (int)
#define WS_AMB   3136     // [3136, 134208)  ambig row list (int)
#define WS_FIDX  134208   // [134208, 265280) final idx (int)
#define WS_BWS   265280   // bf16 B: 512*768 ushort = 196608 floats -> [265280, 461888)
#define WS_NEED  (461888L * 4)

#define MARGIN 0.0625f

typedef __attribute__((ext_vector_type(8))) short bf16x8;
typedef __attribute__((ext_vector_type(4))) float f32x4;

__device__ __forceinline__ unsigned short f2bf(float f) {
    union { float f; unsigned int u; } a; a.f = f;
    return (unsigned short)((a.u + 0x7FFFu + ((a.u >> 16) & 1u)) >> 16);  // RNE
}
__device__ __forceinline__ float bf2f(unsigned short h) {
    union { unsigned int u; float f; } a; a.u = ((unsigned int)h) << 16; return a.f;
}

__global__ void vq_init(float* __restrict__ ws) {
    int i = blockIdx.x * 1024 + threadIdx.x;
    if (i < 3073) ws[i] = 0.0f;   // lpart, hist, e2, cnt
}

__global__ void vq_e2(const float* __restrict__ e, float* __restrict__ e2) {
    int c = blockIdx.x;
    int l = threadIdx.x;  // 64
    float4 v = *(const float4*)(e + c * D + l * 4);
    float s = v.x * v.x + v.y * v.y + v.z * v.z + v.w * v.w;
    #pragma unroll
    for (int off = 32; off; off >>= 1) s += __shfl_xor(s, off);
    if (l == 0) e2[c] = s;
}

// B_ws[n][768] = [eh(256) | eh(256) | el(256)]  (bf16 raw ushort)
__global__ void vq_convB(const float* __restrict__ e, unsigned short* __restrict__ B) {
    int n = blockIdx.x, d = threadIdx.x;
    float v = e[n * D + d];
    unsigned short h = f2bf(v);
    unsigned short l = f2bf(v - bf2f(h));
    B[n * 768 + d]       = h;
    B[n * 768 + 256 + d] = h;
    B[n * 768 + 512 + d] = l;
}

// 128x512 block tile, 8 waves as 2(M)x4(N), 24 K-slabs of 32.
// slab order pairs (i, i+16) so the zh A-stage is reused for the zh*el slab.
__global__ __launch_bounds__(512, 2)
void vq_gemm(const float* __restrict__ z, const unsigned short* __restrict__ Bws,
             const float* __restrict__ e2, int* __restrict__ fidx,
             int* __restrict__ acnt, int* __restrict__ alist) {
    __shared__ __align__(16) unsigned short As[128 * 32];   // 8 KB
    __shared__ __align__(16) unsigned short Bs[512 * 32];   // 32 KB
    __shared__ float red[128 * 4 * 3];                      // 6 KB

    const int tid = threadIdx.x;
    const int w = tid >> 6, l = tid & 63, q = l >> 4, ln = l & 15;
    const int wm = w >> 2, wn = w & 3;
    const long row0 = (long)blockIdx.x * 128;

    f32x4 acc[4][8];
    #pragma unroll
    for (int mt = 0; mt < 4; ++mt)
        #pragma unroll
        for (int nt = 0; nt < 8; ++nt) acc[mt][nt] = (f32x4){0.f, 0.f, 0.f, 0.f};

    for (int p = 0; p < 24; ++p) {
        const int s  = (p < 16) ? ((p >> 1) + (p & 1) * 16) : (p - 8);
        const bool doA = (p >= 16) || ((p & 1) == 0);
        const bool lo  = (s >= 8) && (s < 16);
        const int d0 = (s < 8 ? s : (s < 16 ? s - 8 : s - 16)) * 32;
        const int k0 = s * 32;
        __syncthreads();              // previous slab fully consumed
        // ---- A stage: fp32 -> bf16 (hi or lo) on the fly ----
        if (doA) {
            #pragma unroll
            for (int j = 0; j < 2; ++j) {
                int c = j * 512 + tid;
                int row = c >> 3, col4 = (c & 7) * 4;
                float4 av = *(const float4*)(z + (row0 + row) * D + d0 + col4);
                unsigned short h0 = f2bf(av.x), h1 = f2bf(av.y), h2 = f2bf(av.z), h3 = f2bf(av.w);
                if (lo) {
                    h0 = f2bf(av.x - bf2f(h0)); h1 = f2bf(av.y - bf2f(h1));
                    h2 = f2bf(av.z - bf2f(h2)); h3 = f2bf(av.w - bf2f(h3));
                }
                *(ushort4*)&As[row * 32 + col4] = make_ushort4(h0, h1, h2, h3);
            }
        }
        // ---- B stage: async global->LDS, 16B per lane, 4 chunks per thread ----
        #pragma unroll
        for (int jj = 0; jj < 4; ++jj) {
            int c = w * 256 + jj * 64 + l;                 // 16B chunk index [0,2048)
            int n = c >> 2, kc = (c & 3) * 8;              // Bs row, ushort offset
            const unsigned short* g = Bws + n * 768 + k0 + kc;
            unsigned short* ldsb = &Bs[(w * 256 + jj * 64) * 8];
            __builtin_amdgcn_global_load_lds(
                (const __attribute__((address_space(1))) void*)g,
                (__attribute__((address_space(3))) void*)ldsb, 16, 0, 0);
        }
        __syncthreads();
        // ---- frags + 32 MFMA ----
        bf16x8 af[4], bfr[8];
        #pragma unroll
        for (int mt = 0; mt < 4; ++mt)
            af[mt] = *(const bf16x8*)&As[(wm * 64 + mt * 16 + ln) * 32 + q * 8];
        #pragma unroll
        for (int nt = 0; nt < 8; ++nt)
            bfr[nt] = *(const bf16x8*)&Bs[(wn * 128 + nt * 16 + ln) * 32 + q * 8];
        #pragma unroll
        for (int mt = 0; mt < 4; ++mt)
            #pragma unroll
            for (int nt = 0; nt < 8; ++nt)
                acc[mt][nt] = __builtin_amdgcn_mfma_f32_16x16x32_bf16(af[mt], bfr[nt], acc[mt][nt], 0, 0, 0);
    }

    // ---- per-row top-2 of sim = e2[col] - 2*dot over wave's 128 cols ----
    float e2v[8];
    #pragma unroll
    for (int nt = 0; nt < 8; ++nt) e2v[nt] = e2[wn * 128 + nt * 16 + ln];

    #pragma unroll
    for (int mt = 0; mt < 4; ++mt) {
        #pragma unroll
        for (int r = 0; r < 4; ++r) {
            float v1 = -3.0e38f, v2 = -3.0e38f; int i1 = 0;
            #pragma unroll
            for (int nt = 0; nt < 8; ++nt) {
                float v = e2v[nt] - 2.0f * acc[mt][nt][r];
                int c = wn * 128 + nt * 16 + ln;
                if (v > v1) { v2 = v1; v1 = v; i1 = c; }
                else if (v > v2) v2 = v;
            }
            #pragma unroll
            for (int off = 1; off < 16; off <<= 1) {   // 16-lane group butterfly
                float ov1 = __shfl_xor(v1, off);
                float ov2 = __shfl_xor(v2, off);
                int   oi1 = __shfl_xor(i1, off);
                if (ov1 > v1 || (ov1 == v1 && oi1 < i1)) {
                    v2 = fmaxf(v1, ov2); v1 = ov1; i1 = oi1;
                } else {
                    v2 = fmaxf(v2, ov1);
                }
            }
            if (ln == 0) {
                int rr = wm * 64 + mt * 16 + q * 4 + r;  // block-local row
                red[rr * 12 + wn * 3 + 0] = v1;
                red[rr * 12 + wn * 3 + 1] = (float)i1;
                red[rr * 12 + wn * 3 + 2] = v2;
            }
        }
    }
    __syncthreads();
    // ---- 4-way col-group merge (ascending group order keeps lower-index ties) ----
    if (tid < 128) {
        float v1 = -3.0e38f, v2 = -3.0e38f; int i1 = 0;
        #pragma unroll
        for (int g = 0; g < 4; ++g) {
            float rv1 = red[tid * 12 + g * 3 + 0];
            int   ri  = (int)red[tid * 12 + g * 3 + 1];
            float rv2 = red[tid * 12 + g * 3 + 2];
            if (rv1 > v1) { v2 = fmaxf(v1, rv2); v1 = rv1; i1 = ri; }
            else v2 = fmaxf(v2, rv1);
        }
        fidx[row0 + tid] = i1;
        if (v1 - v2 < MARGIN) {
            int ppos = atomicAdd(acnt, 1);
            alist[ppos] = (int)(row0 + tid);
        }
    }
}

// exact fp32 re-argmax for margin-ambiguous rows
__global__ __launch_bounds__(256)
void vq_refine(const float* __restrict__ z, const float* __restrict__ e,
               const float* __restrict__ e2, const int* __restrict__ acnt,
               const int* __restrict__ alist, int* __restrict__ fidx) {
    __shared__ float zs[D];
    __shared__ float bv[256];
    __shared__ int   bi[256];
    const int t = threadIdx.x;
    const int n = *acnt;
    for (int j = blockIdx.x; j < n; j += gridDim.x) {
        const long row = alist[j];
        __syncthreads();
        zs[t] = z[row * D + t];
        __syncthreads();
        float best = -3.0e38f; int bidx = 0;
        for (int c = t; c < NC; c += 256) {
            float s0 = 0.f, s1 = 0.f, s2 = 0.f, s3 = 0.f;
            for (int d = 0; d < D; d += 4) {
                float4 ev = *(const float4*)(e + c * D + d);
                s0 = fmaf(zs[d],     ev.x, s0);
                s1 = fmaf(zs[d + 1], ev.y, s1);
                s2 = fmaf(zs[d + 2], ev.z, s2);
                s3 = fmaf(zs[d + 3], ev.w, s3);
            }
            float v = e2[c] - 2.0f * ((s0 + s1) + (s2 + s3));
            if (v > best || (v == best && c < bidx)) { best = v; bidx = c; }
        }
        bv[t] = best; bi[t] = bidx;
        __syncthreads();
        for (int off = 128; off; off >>= 1) {
            if (t < off) {
                if (bv[t + off] > bv[t] || (bv[t + off] == bv[t] && bi[t + off] < bi[t])) {
                    bv[t] = bv[t + off]; bi[t] = bi[t + off];
                }
            }
            __syncthreads();
        }
        if (t == 0) fidx[row] = bi[0];
        __syncthreads();
    }
}

// idx output + histogram via LDS (64 blocks -> <=64 serialized atomics per bin)
__global__ __launch_bounds__(256)
void vq_hist(const int* __restrict__ fidx, float* __restrict__ out,
             float* __restrict__ hist) {
    __shared__ int h[NC];
    const int t = threadIdx.x;
    h[t] = 0; h[t + 256] = 0;
    __syncthreads();
    const long base = (long)blockIdx.x * 2048;
    #pragma unroll
    for (int j = 0; j < 8; ++j) {
        long i = base + j * 256 + t;
        int idx = fidx[i];
        out[OFF_IDX + i] = (float)idx;
        atomicAdd(&h[idx], 1);
    }
    __syncthreads();
    #pragma unroll
    for (int j = 0; j < 2; ++j) {
        int k = j * 256 + t;
        int c = h[k];
        if (c) atomicAdd(&hist[k], (float)c);
    }
}

// pure streaming epilogue: z_q_st + per-block loss partial. No atomics.
__global__ __launch_bounds__(256)
void vq_epi(const float* __restrict__ z, const float* __restrict__ e,
            const int* __restrict__ fidx, float* __restrict__ out,
            float* __restrict__ lpart) {
    __shared__ int idxs[64];
    __shared__ float rs[4];
    const int t = threadIdx.x, lane = t & 63, w = t >> 6;
    const long row0 = (long)blockIdx.x * 64;
    if (t < 64) idxs[t] = fidx[row0 + t];
    __syncthreads();
    float ls = 0.f;
    #pragma unroll 4
    for (int j = 0; j < 16; ++j) {
        const int r = w * 16 + j;
        const long row = row0 + r;
        const int idx = idxs[r];
        float4 zv = *(const float4*)(z + row * D + lane * 4);
        float4 ev = *(const float4*)(e + (long)idx * D + lane * 4);
        float4 dq;
        dq.x = ev.x - zv.x; dq.y = ev.y - zv.y; dq.z = ev.z - zv.z; dq.w = ev.w - zv.w;
        float4 o;
        o.x = zv.x + dq.x; o.y = zv.y + dq.y; o.z = zv.z + dq.z; o.w = zv.w + dq.w;
        *(float4*)(out + OFF_ZQ + row * D + lane * 4) = o;
        ls += dq.x * dq.x + dq.y * dq.y + dq.z * dq.z + dq.w * dq.w;
    }
    #pragma unroll
    for (int off = 32; off; off >>= 1) ls += __shfl_xor(ls, off);
    if (lane == 0) rs[w] = ls;
    __syncthreads();
    if (t == 0) lpart[blockIdx.x] = rs[0] + rs[1] + rs[2] + rs[3];
}

__global__ void vq_fin(const float* __restrict__ ws, float* __restrict__ out) {
    __shared__ float sred[16];
    const int t = threadIdx.x, lane = t & 63, w = t >> 6;  // 1024 threads
    float s = ws[WS_LPART + t] + ws[WS_LPART + t + 1024];
    #pragma unroll
    for (int off = 32; off; off >>= 1) s += __shfl_xor(s, off);
    if (lane == 0) sred[w] = s;
    __syncthreads();
    if (t == 0) {
        float tot = 0.f;
        #pragma unroll
        for (int i = 0; i < 16; ++i) tot += sred[i];
        float m = tot / 33554432.0f;     // mean((z_q - z)^2)
        out[OFF_VQ] = m;
        out[OFF_CM] = 0.25f * m;
    }
    if (t < NC) out[OFF_HIST + t] = ws[WS_HIST + t];
}

// ================= fallback (ws too small): round-2 fp32 path =================
__global__ __launch_bounds__(256, 2)
void vq_main_fb(const float* __restrict__ z, const float* __restrict__ e,
                const float* __restrict__ e2, float* __restrict__ out,
                float* __restrict__ ws_loss, float* __restrict__ ws_hist) {
    __shared__ __align__(16) float z_s[32][D];
    __shared__ __align__(16) float e_s[16][NC + 4];
    __shared__ int   idx_s[32];
    __shared__ float red_s[4];
    const int tid = threadIdx.x, lane = tid & 63, w = tid >> 6;
    const long row0 = (long)blockIdx.x * 32;
    {
        const float4* zg = (const float4*)(z + row0 * D);
        float4* zs = (float4*)(&z_s[0][0]);
        #pragma unroll
        for (int i = 0; i < 8; ++i) zs[i * 256 + tid] = zg[i * 256 + tid];
    }
    float acc[8][8];
    #pragma unroll
    for (int r = 0; r < 8; ++r)
        #pragma unroll
        for (int c = 0; c < 8; ++c) acc[r][c] = 0.0f;
    const int r0 = w * 8, c_lo = lane * 4;
    for (int kc = 0; kc < D; kc += 16) {
        __syncthreads();
        #pragma unroll
        for (int p = 0; p < 8; ++p) {
            int c = p * 64 + (tid >> 2), kk4 = (tid & 3) * 4;
            float4 v = *(const float4*)(e + c * D + kc + kk4);
            e_s[kk4 + 0][c] = v.x; e_s[kk4 + 1][c] = v.y;
            e_s[kk4 + 2][c] = v.z; e_s[kk4 + 3][c] = v.w;
        }
        __syncthreads();
        #pragma unroll
        for (int k4 = 0; k4 < 16; k4 += 4) {
            float zr[8][4];
            #pragma unroll
            for (int r = 0; r < 8; ++r) *(float4*)zr[r] = *(const float4*)&z_s[r0 + r][kc + k4];
            #pragma unroll
            for (int kk = 0; kk < 4; ++kk) {
                float ev[8];
                *(float4*)&ev[0] = *(const float4*)&e_s[k4 + kk][c_lo];
                *(float4*)&ev[4] = *(const float4*)&e_s[k4 + kk][c_lo + 256];
                #pragma unroll
                for (int r = 0; r < 8; ++r)
                    #pragma unroll
                    for (int c = 0; c < 8; ++c) acc[r][c] = fmaf(zr[r][kk], ev[c], acc[r][c]);
            }
        }
    }
    float e2v[8];
    #pragma unroll
    for (int g = 0; g < 2; ++g)
        #pragma unroll
        for (int i = 0; i < 4; ++i) e2v[g * 4 + i] = e2[g * 256 + c_lo + i];
    #pragma unroll
    for (int r = 0; r < 8; ++r) {
        float bvv = -3.0e38f; int bc = 0;
        #pragma unroll
        for (int c = 0; c < 8; ++c) {
            int col = (c >> 2) * 256 + c_lo + (c & 3);
            float v = e2v[c] - 2.0f * acc[r][c];
            if (v > bvv) { bvv = v; bc = col; }
        }
        #pragma unroll
        for (int off = 32; off; off >>= 1) {
            float ov = __shfl_xor(bvv, off); int oc = __shfl_xor(bc, off);
            if (ov > bvv || (ov == bvv && oc < bc)) { bvv = ov; bc = oc; }
        }
        if (lane == 0) idx_s[r0 + r] = bc;
    }
    __syncthreads();
    if (tid < 32) {
        int bc = idx_s[tid];
        out[OFF_IDX + row0 + tid] = (float)bc;
        atomicAdd(&ws_hist[bc], 1.0f);
    }
    float lsum = 0.0f;
    for (int r = 0; r < 32; ++r) {
        int idx = idx_s[r];
        float ev = e[idx * D + tid];
        float zv = z_s[r][tid];
        float dq = ev - zv;
        out[OFF_ZQ + (row0 + r) * D + tid] = zv + dq;
        lsum += dq * dq;
    }
    #pragma unroll
    for (int off = 32; off; off >>= 1) lsum += __shfl_xor(lsum, off);
    if (lane == 0) red_s[w] = lsum;
    __syncthreads();
    if (tid == 0) atomicAdd(ws_loss, red_s[0] + red_s[1] + red_s[2] + red_s[3]);
}

__global__ void vq_init_fb(float* __restrict__ ws) {
    int t = threadIdx.x;
    if (t < 513) ws[t] = 0.0f;
}
__global__ void vq_fin_fb(const float* __restrict__ ws, float* __restrict__ out) {
    int t = blockIdx.x * blockDim.x + threadIdx.x;
    if (t < NC) out[OFF_HIST + t] = ws[1 + t];
    if (t == NC) {
        float m = ws[0] / 33554432.0f;
        out[OFF_VQ] = m; out[OFF_CM] = 0.25f * m;
    }
}

extern "C" void kernel_launch(void* const* d_in, const int* in_sizes, int n_in,
                              void* d_out, int out_size, void* d_ws, size_t ws_size,
                              hipStream_t stream) {
    const float* z = (const float*)d_in[0];
    const float* e = (const float*)d_in[1];
    float* out = (float*)d_out;
    float* ws  = (float*)d_ws;

    if (ws_size >= (size_t)WS_NEED) {
        float* lpart = ws + WS_LPART;
        float* hist  = ws + WS_HIST;
        float* e2    = ws + WS_E2;
        int*   acnt  = (int*)(ws + WS_CNT);
        int*   alist = (int*)(ws + WS_AMB);
        int*   fidx  = (int*)(ws + WS_FIDX);
        unsigned short* Bws = (unsigned short*)(ws + WS_BWS);

        vq_init<<<4, 1024, 0, stream>>>(ws);
        vq_e2<<<NC, 64, 0, stream>>>(e, e2);
        vq_convB<<<NC, 256, 0, stream>>>(e, Bws);
        vq_gemm<<<1024, 512, 0, stream>>>(z, Bws, e2, fidx, acnt, alist);
        vq_refine<<<256, 256, 0, stream>>>(z, e, e2, acnt, alist, fidx);
        vq_hist<<<64, 256, 0, stream>>>(fidx, out, hist);
        vq_epi<<<2048, 256, 0, stream>>>(z, e, fidx, out, lpart);
        vq_fin<<<1, 1024, 0, stream>>>(ws, out);
    } else {
        float* ws_loss = ws;
        float* ws_hist = ws + 1;
        float* ws_e2   = ws + 513;
        vq_init_fb<<<1, 1024, 0, stream>>>(ws);
        vq_e2<<<NC, 64, 0, stream>>>(e, ws_e2);
        vq_main_fb<<<4096, 256, 0, stream>>>(z, e, ws_e2, out, ws_loss, ws_hist);
        vq_fin_fb<<<3, 256, 0, stream>>>(ws, out);
    }
}

// Round 5
// 388.479 us; speedup vs baseline: 1.9647x; 1.3176x over previous
//
#include <hip/hip_runtime.h>
#include <hip/hip_bf16.h>

#define D 256
#define NC 512
#define NROWS 131072L

// out layout (fp32 elements), reference return order
#define OFF_ZQ   0L
#define OFF_VQ   33554432L
#define OFF_CM   33554433L
#define OFF_IDX  33554434L
#define OFF_HIST 33685506L

// ws float offsets
#define WS_LPART 0        // [0, 2048)       per-block loss partials
#define WS_HIST  2048     // [2048, 2560)
#define WS_E2    2560     // [2560, 3072)
#define WS_CNT   3072     // ambig count (int), padded to 3136
#define WS_AMB   3136     // [3136, 134208)   ambig row list (int)
#define WS_FIDX  134208   // [134208, 265280) final idx (int)
#define WS_BK    265280   // bf16 eh, k-slab-major: 8 slabs x 512 codes x 32 k = 131072 ushort = 65536 f
#define WS_NEED  (330816L * 4)

#define MARGIN 1.25f

typedef __attribute__((ext_vector_type(8))) short bf16x8;
typedef __attribute__((ext_vector_type(4))) float f32x4;

#define AS1 __attribute__((address_space(1)))
#define AS3 __attribute__((address_space(3)))

__device__ __forceinline__ unsigned short f2bf(float f) {
    union { float f; unsigned int u; } a; a.f = f;
    return (unsigned short)((a.u + 0x7FFFu + ((a.u >> 16) & 1u)) >> 16);  // RNE
}

__global__ void vq_init(float* __restrict__ ws) {
    int i = blockIdx.x * 1024 + threadIdx.x;
    if (i < 3073) ws[i] = 0.0f;   // lpart, hist, e2, cnt
}

__global__ void vq_e2(const float* __restrict__ e, float* __restrict__ e2) {
    int c = blockIdx.x;
    int l = threadIdx.x;  // 64
    float4 v = *(const float4*)(e + c * D + l * 4);
    float s = v.x * v.x + v.y * v.y + v.z * v.z + v.w * v.w;
    #pragma unroll
    for (int off = 32; off; off >>= 1) s += __shfl_xor(s, off);
    if (l == 0) e2[c] = s;
}

// Bk[slab][code][32] = bf16(e[code][slab*32 .. +32))   (hi part only)
__global__ void vq_convB(const float* __restrict__ e, unsigned short* __restrict__ Bk) {
    int code = blockIdx.x, k = threadIdx.x;
    unsigned short h = f2bf(e[code * D + k]);
    Bk[((k >> 5) * NC + code) * 32 + (k & 31)] = h;
}

// 64x512 block tile, 8 waves as 2(M)x4(N), 8 K-slabs of 32. z staged once.
__global__ __launch_bounds__(512, 4)
void vq_gemm(const float* __restrict__ z, const unsigned short* __restrict__ Bk,
             const float* __restrict__ e2, int* __restrict__ fidx,
             int* __restrict__ acnt, int* __restrict__ alist) {
    __shared__ __align__(16) unsigned short zh[64 * 264];   // 33 KB, +8 pad (2-way free)
    __shared__ __align__(16) unsigned short Bs[512 * 32];   // 32 KB, 16B-xor-swizzled
    __shared__ float red[64 * 4 * 3];                       // 3 KB

    const int tid = threadIdx.x;
    const int w = tid >> 6, l = tid & 63, q = l >> 4, ln = l & 15;
    const int wm = w >> 2, wn = w & 3;
    const long row0 = (long)blockIdx.x * 64;

    // ---- stage z once: 64 rows x 256 f32 -> bf16 hi, padded LDS ----
    #pragma unroll
    for (int j = 0; j < 8; ++j) {
        int c = j * 512 + tid;              // float4 chunk 0..4095
        int row = c >> 6, c4 = (c & 63) * 4;
        float4 av = *(const float4*)(z + (row0 + row) * D + c4);
        *(ushort4*)&zh[row * 264 + c4] =
            make_ushort4(f2bf(av.x), f2bf(av.y), f2bf(av.z), f2bf(av.w));
    }

    // ---- loop-invariant B frag LDS addresses (swizzled, 2-way free) ----
    int bidx[8];
    #pragma unroll
    for (int nt = 0; nt < 8; ++nt) {
        int code = wn * 128 + nt * 16 + ln;
        int c = code * 4 + q;               // 16B chunk in slab
        int d = c ^ ((code >> 1) & 3);      // involution
        bidx[nt] = d * 8;                   // ushort index
    }

    f32x4 acc[2][8];
    #pragma unroll
    for (int mt = 0; mt < 2; ++mt)
        #pragma unroll
        for (int nt = 0; nt < 8; ++nt) acc[mt][nt] = (f32x4){0.f, 0.f, 0.f, 0.f};

    for (int s = 0; s < 8; ++s) {
        __syncthreads();                    // zh ready (s=0) / prev Bs consumed
        const unsigned short* slabB = Bk + s * (NC * 32);
        #pragma unroll
        for (int j = 0; j < 4; ++j) {
            int dd = j * 512 + tid;         // LDS chunk: lane-contiguous per wave
            int cc = dd ^ ((dd >> 3) & 3);  // global chunk (same involution)
            __builtin_amdgcn_global_load_lds((const AS1 void*)(slabB + cc * 8),
                                             (AS3 void*)(Bs + dd * 8), 16, 0, 0);
        }
        __syncthreads();                    // Bs[s] ready (vmcnt drain)
        bf16x8 af[2], bfr[8];
        #pragma unroll
        for (int mt = 0; mt < 2; ++mt)
            af[mt] = *(const bf16x8*)&zh[(wm * 32 + mt * 16 + ln) * 264 + s * 32 + q * 8];
        #pragma unroll
        for (int nt = 0; nt < 8; ++nt)
            bfr[nt] = *(const bf16x8*)&Bs[bidx[nt]];
        #pragma unroll
        for (int mt = 0; mt < 2; ++mt)
            #pragma unroll
            for (int nt = 0; nt < 8; ++nt)
                acc[mt][nt] = __builtin_amdgcn_mfma_f32_16x16x32_bf16(af[mt], bfr[nt], acc[mt][nt], 0, 0, 0);
    }

    // ---- per-row top-2 of sim = e2[col] - 2*dot over wave's 128 cols ----
    float e2v[8];
    #pragma unroll
    for (int nt = 0; nt < 8; ++nt) e2v[nt] = e2[wn * 128 + nt * 16 + ln];

    #pragma unroll
    for (int mt = 0; mt < 2; ++mt) {
        #pragma unroll
        for (int r = 0; r < 4; ++r) {
            float v1 = -3.0e38f, v2 = -3.0e38f; int i1 = 0;
            #pragma unroll
            for (int nt = 0; nt < 8; ++nt) {
                float v = e2v[nt] - 2.0f * acc[mt][nt][r];
                int c = wn * 128 + nt * 16 + ln;
                if (v > v1) { v2 = v1; v1 = v; i1 = c; }
                else if (v > v2) v2 = v;
            }
            #pragma unroll
            for (int off = 1; off < 16; off <<= 1) {   // 16-lane group butterfly
                float ov1 = __shfl_xor(v1, off);
                float ov2 = __shfl_xor(v2, off);
                int   oi1 = __shfl_xor(i1, off);
                if (ov1 > v1 || (ov1 == v1 && oi1 < i1)) {
                    v2 = fmaxf(v1, ov2); v1 = ov1; i1 = oi1;
                } else {
                    v2 = fmaxf(v2, ov1);
                }
            }
            if (ln == 0) {
                int rr = wm * 32 + mt * 16 + q * 4 + r;  // block-local row
                red[rr * 12 + wn * 3 + 0] = v1;
                red[rr * 12 + wn * 3 + 1] = (float)i1;
                red[rr * 12 + wn * 3 + 2] = v2;
            }
        }
    }
    __syncthreads();
    // ---- 4-way col-group merge (ascending order keeps lower-index ties) ----
    if (tid < 64) {
        float v1 = -3.0e38f, v2 = -3.0e38f; int i1 = 0;
        #pragma unroll
        for (int g = 0; g < 4; ++g) {
            float rv1 = red[tid * 12 + g * 3 + 0];
            int   ri  = (int)red[tid * 12 + g * 3 + 1];
            float rv2 = red[tid * 12 + g * 3 + 2];
            if (rv1 > v1) { v2 = fmaxf(v1, rv2); v1 = rv1; i1 = ri; }
            else v2 = fmaxf(v2, rv1);
        }
        fidx[row0 + tid] = i1;
        if (v1 - v2 < MARGIN) {
            int ppos = atomicAdd(acnt, 1);
            alist[ppos] = (int)(row0 + tid);
        }
    }
}

// exact fp32 re-argmax for margin-ambiguous rows, 32-row groups share the e-stream
__global__ __launch_bounds__(256, 2)
void vq_refine(const float* __restrict__ z, const float* __restrict__ e,
               const float* __restrict__ e2, const int* __restrict__ acnt,
               const int* __restrict__ alist, int* __restrict__ fidx) {
    __shared__ __align__(16) float z_s[32][D];        // 32 KB
    __shared__ __align__(16) float e_s[16][NC + 4];   // 33 KB
    __shared__ int rowg[32];
    __shared__ int idx_s[32];
    const int tid = threadIdx.x, lane = tid & 63, w = tid >> 6;
    const int cnt = *acnt;
    for (int g = blockIdx.x; g * 32 < cnt; g += gridDim.x) {
        const int base = g * 32;
        __syncthreads();   // prev iteration fully done with z_s/rowg/idx_s
        if (tid < 32) rowg[tid] = alist[min(base + tid, cnt - 1)];  // pad w/ first row
        __syncthreads();
        #pragma unroll
        for (int j = 0; j < 8; ++j) {      // gather 32 z rows
            int c = j * 256 + tid, rl = c >> 6, c4 = (c & 63) * 4;
            *(float4*)&z_s[rl][c4] = *(const float4*)(z + (long)rowg[rl] * D + c4);
        }
        float acc[8][8];
        #pragma unroll
        for (int r = 0; r < 8; ++r)
            #pragma unroll
            for (int c = 0; c < 8; ++c) acc[r][c] = 0.0f;
        const int r0 = w * 8, c_lo = lane * 4;
        for (int kc = 0; kc < D; kc += 16) {
            __syncthreads();
            #pragma unroll
            for (int p = 0; p < 8; ++p) {
                int c = p * 64 + (tid >> 2), kk4 = (tid & 3) * 4;
                float4 v = *(const float4*)(e + c * D + kc + kk4);
                e_s[kk4 + 0][c] = v.x; e_s[kk4 + 1][c] = v.y;
                e_s[kk4 + 2][c] = v.z; e_s[kk4 + 3][c] = v.w;
            }
            __syncthreads();
            #pragma unroll
            for (int k4 = 0; k4 < 16; k4 += 4) {
                float zr[8][4];
                #pragma unroll
                for (int r = 0; r < 8; ++r) *(float4*)zr[r] = *(const float4*)&z_s[r0 + r][kc + k4];
                #pragma unroll
                for (int kk = 0; kk < 4; ++kk) {
                    float ev[8];
                    *(float4*)&ev[0] = *(const float4*)&e_s[k4 + kk][c_lo];
                    *(float4*)&ev[4] = *(const float4*)&e_s[k4 + kk][c_lo + 256];
                    #pragma unroll
                    for (int r = 0; r < 8; ++r)
                        #pragma unroll
                        for (int c = 0; c < 8; ++c) acc[r][c] = fmaf(zr[r][kk], ev[c], acc[r][c]);
                }
            }
        }
        float e2v[8];
        #pragma unroll
        for (int gg = 0; gg < 2; ++gg)
            #pragma unroll
            for (int i = 0; i < 4; ++i) e2v[gg * 4 + i] = e2[gg * 256 + c_lo + i];
        #pragma unroll
        for (int r = 0; r < 8; ++r) {
            float bvv = -3.0e38f; int bc = 0;
            #pragma unroll
            for (int c = 0; c < 8; ++c) {
                int col = (c >> 2) * 256 + c_lo + (c & 3);
                float v = e2v[c] - 2.0f * acc[r][c];
                if (v > bvv) { bvv = v; bc = col; }
            }
            #pragma unroll
            for (int off = 32; off; off >>= 1) {
                float ov = __shfl_xor(bvv, off); int oc = __shfl_xor(bc, off);
                if (ov > bvv || (ov == bvv && oc < bc)) { bvv = ov; bc = oc; }
            }
            if (lane == 0) idx_s[r0 + r] = bc;
        }
        __syncthreads();
        if (tid < 32 && base + tid < cnt) fidx[rowg[tid]] = idx_s[tid];
    }
}

// idx output + histogram via LDS (64 blocks -> <=64 serialized atomics per bin)
__global__ __launch_bounds__(256)
void vq_hist(const int* __restrict__ fidx, float* __restrict__ out,
             float* __restrict__ hist) {
    __shared__ int h[NC];
    const int t = threadIdx.x;
    h[t] = 0; h[t + 256] = 0;
    __syncthreads();
    const long base = (long)blockIdx.x * 2048;
    #pragma unroll
    for (int j = 0; j < 8; ++j) {
        long i = base + j * 256 + t;
        int idx = fidx[i];
        out[OFF_IDX + i] = (float)idx;
        atomicAdd(&h[idx], 1);
    }
    __syncthreads();
    #pragma unroll
    for (int j = 0; j < 2; ++j) {
        int k = j * 256 + t;
        int c = h[k];
        if (c) atomicAdd(&hist[k], (float)c);
    }
}

// pure streaming epilogue: z_q_st + per-block loss partial. No atomics.
__global__ __launch_bounds__(256)
void vq_epi(const float* __restrict__ z, const float* __restrict__ e,
            const int* __restrict__ fidx, float* __restrict__ out,
            float* __restrict__ lpart) {
    __shared__ int idxs[64];
    __shared__ float rs[4];
    const int t = threadIdx.x, lane = t & 63, w = t >> 6;
    const long row0 = (long)blockIdx.x * 64;
    if (t < 64) idxs[t] = fidx[row0 + t];
    __syncthreads();
    float ls = 0.f;
    #pragma unroll 4
    for (int j = 0; j < 16; ++j) {
        const int r = w * 16 + j;
        const long row = row0 + r;
        const int idx = idxs[r];
        float4 zv = *(const float4*)(z + row * D + lane * 4);
        float4 ev = *(const float4*)(e + (long)idx * D + lane * 4);
        float4 dq;
        dq.x = ev.x - zv.x; dq.y = ev.y - zv.y; dq.z = ev.z - zv.z; dq.w = ev.w - zv.w;
        float4 o;
        o.x = zv.x + dq.x; o.y = zv.y + dq.y; o.z = zv.z + dq.z; o.w = zv.w + dq.w;
        *(float4*)(out + OFF_ZQ + row * D + lane * 4) = o;
        ls += dq.x * dq.x + dq.y * dq.y + dq.z * dq.z + dq.w * dq.w;
    }
    #pragma unroll
    for (int off = 32; off; off >>= 1) ls += __shfl_xor(ls, off);
    if (lane == 0) rs[w] = ls;
    __syncthreads();
    if (t == 0) lpart[blockIdx.x] = rs[0] + rs[1] + rs[2] + rs[3];
}

__global__ void vq_fin(const float* __restrict__ ws, float* __restrict__ out) {
    __shared__ float sred[16];
    const int t = threadIdx.x, lane = t & 63, w = t >> 6;  // 1024 threads
    float s = ws[WS_LPART + t] + ws[WS_LPART + t + 1024];
    #pragma unroll
    for (int off = 32; off; off >>= 1) s += __shfl_xor(s, off);
    if (lane == 0) sred[w] = s;
    __syncthreads();
    if (t == 0) {
        float tot = 0.f;
        #pragma unroll
        for (int i = 0; i < 16; ++i) tot += sred[i];
        float m = tot / 33554432.0f;     // mean((z_q - z)^2)
        out[OFF_VQ] = m;
        out[OFF_CM] = 0.25f * m;
    }
    if (t < NC) out[OFF_HIST + t] = ws[WS_HIST + t];
}

// ================= fallback (ws too small): round-2 fp32 path =================
__global__ __launch_bounds__(256, 2)
void vq_main_fb(const float* __restrict__ z, const float* __restrict__ e,
                const float* __restrict__ e2, float* __restrict__ out,
                float* __restrict__ ws_loss, float* __restrict__ ws_hist) {
    __shared__ __align__(16) float z_s[32][D];
    __shared__ __align__(16) float e_s[16][NC + 4];
    __shared__ int   idx_s[32];
    __shared__ float red_s[4];
    const int tid = threadIdx.x, lane = tid & 63, w = tid >> 6;
    const long row0 = (long)blockIdx.x * 32;
    {
        const float4* zg = (const float4*)(z + row0 * D);
        float4* zs = (float4*)(&z_s[0][0]);
        #pragma unroll
        for (int i = 0; i < 8; ++i) zs[i * 256 + tid] = zg[i * 256 + tid];
    }
    float acc[8][8];
    #pragma unroll
    for (int r = 0; r < 8; ++r)
        #pragma unroll
        for (int c = 0; c < 8; ++c) acc[r][c] = 0.0f;
    const int r0 = w * 8, c_lo = lane * 4;
    for (int kc = 0; kc < D; kc += 16) {
        __syncthreads();
        #pragma unroll
        for (int p = 0; p < 8; ++p) {
            int c = p * 64 + (tid >> 2), kk4 = (tid & 3) * 4;
            float4 v = *(const float4*)(e + c * D + kc + kk4);
            e_s[kk4 + 0][c] = v.x; e_s[kk4 + 1][c] = v.y;
            e_s[kk4 + 2][c] = v.z; e_s[kk4 + 3][c] = v.w;
        }
        __syncthreads();
        #pragma unroll
        for (int k4 = 0; k4 < 16; k4 += 4) {
            float zr[8][4];
            #pragma unroll
            for (int r = 0; r < 8; ++r) *(float4*)zr[r] = *(const float4*)&z_s[r0 + r][kc + k4];
            #pragma unroll
            for (int kk = 0; kk < 4; ++kk) {
                float ev[8];
                *(float4*)&ev[0] = *(const float4*)&e_s[k4 + kk][c_lo];
                *(float4*)&ev[4] = *(const float4*)&e_s[k4 + kk][c_lo + 256];
                #pragma unroll
                for (int r = 0; r < 8; ++r)
                    #pragma unroll
                    for (int c = 0; c < 8; ++c) acc[r][c] = fmaf(zr[r][kk], ev[c], acc[r][c]);
            }
        }
    }
    float e2v[8];
    #pragma unroll
    for (int g = 0; g < 2; ++g)
        #pragma unroll
        for (int i = 0; i < 4; ++i) e2v[g * 4 + i] = e2[g * 256 + c_lo + i];
    #pragma unroll
    for (int r = 0; r < 8; ++r) {
        float bvv = -3.0e38f; int bc = 0;
        #pragma unroll
        for (int c = 0; c < 8; ++c) {
            int col = (c >> 2) * 256 + c_lo + (c & 3);
            float v = e2v[c] - 2.0f * acc[r][c];
            if (v > bvv) { bvv = v; bc = col; }
        }
        #pragma unroll
        for (int off = 32; off; off >>= 1) {
            float ov = __shfl_xor(bvv, off); int oc = __shfl_xor(bc, off);
            if (ov > bvv || (ov == bvv && oc < bc)) { bvv = ov; bc = oc; }
        }
        if (lane == 0) idx_s[r0 + r] = bc;
    }
    __syncthreads();
    if (tid < 32) {
        int bc = idx_s[tid];
        out[OFF_IDX + row0 + tid] = (float)bc;
        atomicAdd(&ws_hist[bc], 1.0f);
    }
    float lsum = 0.0f;
    for (int r = 0; r < 32; ++r) {
        int idx = idx_s[r];
        float ev = e[idx * D + tid];
        float zv = z_s[r][tid];
        float dq = ev - zv;
        out[OFF_ZQ + (row0 + r) * D + tid] = zv + dq;
        lsum += dq * dq;
    }
    #pragma unroll
    for (int off = 32; off; off >>= 1) lsum += __shfl_xor(lsum, off);
    if (lane == 0) red_s[w] = lsum;
    __syncthreads();
    if (tid == 0) atomicAdd(ws_loss, red_s[0] + red_s[1] + red_s[2] + red_s[3]);
}

__global__ void vq_init_fb(float* __restrict__ ws) {
    int t = threadIdx.x;
    if (t < 513) ws[t] = 0.0f;
}
__global__ void vq_fin_fb(const float* __restrict__ ws, float* __restrict__ out) {
    int t = blockIdx.x * blockDim.x + threadIdx.x;
    if (t < NC) out[OFF_HIST + t] = ws[1 + t];
    if (t == NC) {
        float m = ws[0] / 33554432.0f;
        out[OFF_VQ] = m; out[OFF_CM] = 0.25f * m;
    }
}

extern "C" void kernel_launch(void* const* d_in, const int* in_sizes, int n_in,
                              void* d_out, int out_size, void* d_ws, size_t ws_size,
                              hipStream_t stream) {
    const float* z = (const float*)d_in[0];
    const float* e = (const float*)d_in[1];
    float* out = (float*)d_out;
    float* ws  = (float*)d_ws;

    if (ws_size >= (size_t)WS_NEED) {
        float* lpart = ws + WS_LPART;
        float* hist  = ws + WS_HIST;
        float* e2    = ws + WS_E2;
        int*   acnt  = (int*)(ws + WS_CNT);
        int*   alist = (int*)(ws + WS_AMB);
        int*   fidx  = (int*)(ws + WS_FIDX);
        unsigned short* Bk = (unsigned short*)(ws + WS_BK);

        vq_init<<<4, 1024, 0, stream>>>(ws);
        vq_e2<<<NC, 64, 0, stream>>>(e, e2);
        vq_convB<<<NC, 256, 0, stream>>>(e, Bk);
        vq_gemm<<<2048, 512, 0, stream>>>(z, Bk, e2, fidx, acnt, alist);
        vq_refine<<<512, 256, 0, stream>>>(z, e, e2, acnt, alist, fidx);
        vq_hist<<<64, 256, 0, stream>>>(fidx, out, hist);
        vq_epi<<<2048, 256, 0, stream>>>(z, e, fidx, out, lpart);
        vq_fin<<<1, 1024, 0, stream>>>(ws, out);
    } else {
        float* ws_loss = ws;
        float* ws_hist = ws + 1;
        float* ws_e2   = ws + 513;
        vq_init_fb<<<1, 1024, 0, stream>>>(ws);
        vq_e2<<<NC, 64, 0, stream>>>(e, ws_e2);
        vq_main_fb<<<4096, 256, 0, stream>>>(z, e, ws_e2, out, ws_loss, ws_hist);
        vq_fin_fb<<<3, 256, 0, stream>>>(ws, out);
    }
}